// Round 2
// baseline (45381.705 us; speedup 1.0000x reference)
//
#include <hip/hip_runtime.h>

#define BB   256      // batch
#define LAT  256
#define CND  64
#define HID  1024
#define OUTD 128
#define TLEN 512
#define GIN  192      // OUTD + CND
#define G4   4096     // 4*HID

typedef _Float16 f16x8 __attribute__((ext_vector_type(8)));
typedef float    f32x4 __attribute__((ext_vector_type(4)));

#define LOSCALE 2048.0f
#define LOINV   (1.0f / 2048.0f)

__device__ __forceinline__ float fsig(float x) {
  return 1.0f / (1.0f + exp2f(-1.4426950408889634f * x));
}
__device__ __forceinline__ float ftanh_(float x) {
  return 2.0f / (1.0f + exp2f(2.8853900817779268f * (-x))) - 1.0f;
}

// ---------------- prep kernels ----------------

// h0 = lat@Wh^T+bh ; c0 = lat@Wc^T+bc ; x0 = lat@Ws^T+bs
__global__ void prep_init(const float* __restrict__ lat,
                          const float* __restrict__ Wh, const float* __restrict__ bh,
                          const float* __restrict__ Wc, const float* __restrict__ bc,
                          const float* __restrict__ Ws, const float* __restrict__ bs,
                          float* __restrict__ h0, _Float16* __restrict__ hH, _Float16* __restrict__ hL,
                          float* __restrict__ c0, float* __restrict__ x0)
{
  __shared__ float lat_s[8][LAT];
  int tid = threadIdx.x;
  int b0 = blockIdx.y * 8;
  for (int bb = 0; bb < 8; ++bb)
    lat_s[bb][tid] = lat[(size_t)(b0 + bb) * LAT + tid];
  __syncthreads();
  int col = blockIdx.x * 256 + tid;
  if (col >= 2 * HID + OUTD) return;
  const float* wr; float bias; int kind; int cc;
  if (col < HID)            { cc = col;           wr = Wh + (size_t)cc * LAT; bias = bh[cc]; kind = 0; }
  else if (col < 2 * HID)   { cc = col - HID;     wr = Wc + (size_t)cc * LAT; bias = bc[cc]; kind = 1; }
  else                      { cc = col - 2 * HID; wr = Ws + (size_t)cc * LAT; bias = bs[cc]; kind = 2; }
  float acc[8];
#pragma unroll
  for (int bb = 0; bb < 8; ++bb) acc[bb] = bias;
  for (int k = 0; k < LAT; ++k) {
    float wv = wr[k];
#pragma unroll
    for (int bb = 0; bb < 8; ++bb) acc[bb] += lat_s[bb][k] * wv;
  }
  for (int bb = 0; bb < 8; ++bb) {
    int b = b0 + bb;
    if (kind == 0) {
      float v = acc[bb];
      h0[(size_t)b*HID + cc] = v;
      _Float16 hi = (_Float16)v;
      hH[(size_t)b*HID + cc] = hi;
      hL[(size_t)b*HID + cc] = (_Float16)((v - (float)hi) * LOSCALE);
    }
    else if (kind == 1) { c0[(size_t)b*HID + cc] = acc[bb]; }
    else                { x0[(size_t)b*OUTD + cc] = acc[bb]; }
  }
}

// d = x0 - (h0@Wout^T + bout)
__global__ void prep_d(const float* __restrict__ h0, const float* __restrict__ Wout,
                       const float* __restrict__ bout, const float* __restrict__ x0,
                       float* __restrict__ d)
{
  int t = blockIdx.x * 256 + threadIdx.x;   // 32768
  int b = t >> 7, o = t & 127;
  const float* wr = Wout + (size_t)o * HID;
  const float* hr = h0 + (size_t)b * HID;
  float acc = bout[o];
  for (int k = 0; k < HID; ++k) acc += hr[k] * wr[k];
  d[t] = x0[t] - acc;
}

// Weff[n][k] = Whh[n][k] + sum_j Wih[n][j]*Wout[j][k]   (f16 hi/lo out)
__global__ void prep_weff(const float* __restrict__ Whh, const float* __restrict__ Wih,
                          const float* __restrict__ Wout,
                          _Float16* __restrict__ WeffH, _Float16* __restrict__ WeffL)
{
  int k = blockIdx.x * 256 + threadIdx.x;   // grid.x = 4 -> k 0..1023
  int n0 = blockIdx.y * 16;
  float acc[16];
#pragma unroll
  for (int nn = 0; nn < 16; ++nn) acc[nn] = Whh[(size_t)(n0 + nn) * HID + k];
  for (int j = 0; j < OUTD; ++j) {
    float wo = Wout[(size_t)j * HID + k];
#pragma unroll
    for (int nn = 0; nn < 16; ++nn) acc[nn] += Wih[(size_t)(n0 + nn) * GIN + j] * wo;
  }
#pragma unroll
  for (int nn = 0; nn < 16; ++nn) {
    size_t idx = (size_t)(n0 + nn) * HID + k;
    float w = acc[nn];
    _Float16 hi = (_Float16)w;
    WeffH[idx] = hi;
    WeffL[idx] = (_Float16)((w - (float)hi) * LOSCALE);
  }
}

__global__ void prep_wob(const float* __restrict__ Wout, _Float16* __restrict__ Wob) {
  int t = blockIdx.x * 256 + threadIdx.x;
  Wob[t] = (_Float16)Wout[t];
}

// biasR[b][n] = bih+bhh + cond@Wihc^T + bout@Wihx^T ; biasS = biasR + d@Wihx^T
__global__ void prep_bias(const float* __restrict__ cond, const float* __restrict__ Wih,
                          const float* __restrict__ bih, const float* __restrict__ bhh,
                          const float* __restrict__ bout, const float* __restrict__ d,
                          float* __restrict__ biasR, float* __restrict__ biasS)
{
  __shared__ float cond_s[8][CND];
  __shared__ float d_s[8][OUTD];
  int tid = threadIdx.x;
  int b0 = blockIdx.y * 8;
  for (int qq = 0; qq < 2; ++qq) {                      // FIX: load all 512 entries
    int idx = qq * 256 + tid;
    cond_s[idx >> 6][idx & 63] = cond[(size_t)(b0 + (idx >> 6)) * CND + (idx & 63)];
  }
  for (int qq = 0; qq < 4; ++qq) {
    int idx = qq * 256 + tid;
    d_s[idx >> 7][idx & 127] = d[(size_t)(b0 + (idx >> 7)) * OUTD + (idx & 127)];
  }
  __syncthreads();
  int n = blockIdx.x * 256 + tid;
  const float* wi = Wih + (size_t)n * GIN;
  float base = bih[n] + bhh[n];
  float aR[8], aS[8];
#pragma unroll
  for (int bb = 0; bb < 8; ++bb) { aR[bb] = 0.f; aS[bb] = 0.f; }
  for (int c = 0; c < CND; ++c) {
    float wv = wi[OUTD + c];
#pragma unroll
    for (int bb = 0; bb < 8; ++bb) aR[bb] += cond_s[bb][c] * wv;
  }
  for (int o = 0; o < OUTD; ++o) {
    float wv = wi[o];
    float bo = bout[o];
#pragma unroll
    for (int bb = 0; bb < 8; ++bb) { aR[bb] += bo * wv; aS[bb] += d_s[bb][o] * wv; }
  }
  for (int bb = 0; bb < 8; ++bb) {
    size_t idx = (size_t)(b0 + bb) * G4 + n;
    biasR[idx] = base + aR[bb];
    biasS[idx] = base + aR[bb] + aS[bb];
  }
}

// ---------------- grid barrier ----------------

__device__ __forceinline__ void gridbar(unsigned* flags, unsigned* go, unsigned gen) {
  __syncthreads();
  if (blockIdx.x == 0) {
    int i = threadIdx.x;
    if (i > 0) {
      long cnt = 0;
      while (__hip_atomic_load(flags + i * 32, __ATOMIC_ACQUIRE, __HIP_MEMORY_SCOPE_AGENT) != gen) {
        if (++cnt > 50000000L) break;   // safety: wrong-but-not-hung
        __builtin_amdgcn_s_sleep(1);
      }
    }
    __syncthreads();
    if (i == 0)
      __hip_atomic_store(go, gen, __ATOMIC_RELEASE, __HIP_MEMORY_SCOPE_AGENT);
    __syncthreads();
  } else {
    if (threadIdx.x == 0) {
      __hip_atomic_store(flags + blockIdx.x * 32, gen, __ATOMIC_RELEASE, __HIP_MEMORY_SCOPE_AGENT);
      long cnt = 0;
      while (__hip_atomic_load(go, __ATOMIC_ACQUIRE, __HIP_MEMORY_SCOPE_AGENT) != gen) {
        if (++cnt > 50000000L) break;
        __builtin_amdgcn_s_sleep(1);
      }
    }
    __syncthreads();
  }
}

// ---------------- main persistent kernel ----------------

__global__ __launch_bounds__(256)
void lstm_main(_Float16* hHbuf, _Float16* hLbuf, const float* __restrict__ c0,
               const float* __restrict__ biasR, const float* __restrict__ biasS,
               const _Float16* __restrict__ WeffH, const _Float16* __restrict__ WeffL,
               const _Float16* __restrict__ Wob,
               const float* __restrict__ bout, const int* __restrict__ len,
               float* __restrict__ out, unsigned* flags, unsigned* go)
{
  int wg = blockIdx.x;          // 256 wgs
  // XCD-aware mapping (round-robin heuristic: wg%8 = xcd)
  int xcd = wg & 7, slot = wg >> 3;
  int q = slot >> 2, mt = slot & 3;
  int nt = q * 8 + xcd;         // 16 h-columns; distinct 2MB W-slice per XCD (fits L2)
  int tid = threadIdx.x;
  int w = tid >> 6, lane = tid & 63;
  int l15 = lane & 15, lh = lane >> 4;
  int bA  = mt * 64 + w * 16 + l15;      // A-frag row (h load)
  int bD0 = mt * 64 + w * 16 + lh * 4;   // C/D row base (+r)
  int j = nt * 16 + l15;                 // h column this lane owns in C/D
  float c[4];
  int mylen[4];
#pragma unroll
  for (int r = 0; r < 4; ++r) {
    c[r] = c0[(size_t)(bD0 + r) * HID + j];
    mylen[r] = len[bD0 + r];
  }
  bool doy = (nt < 8);                   // q==0 -> one y-wg group per XCD
  int o = nt * 16 + l15;
  float bo = doy ? bout[o] : 0.0f;
  size_t aoff = (size_t)bA * HID + lh * 8;
  size_t wrow[4];
#pragma unroll
  for (int g = 0; g < 4; ++g) wrow[g] = (size_t)(g * HID + nt * 16 + l15) * HID + lh * 8;
  size_t yrow = (size_t)o * HID + lh * 8;

  for (int t = 0; t < TLEN; ++t) {
    const float* bias = t ? biasR : biasS;
    const _Float16* hinH = hHbuf + (size_t)(t & 1) * (BB * HID);
    const _Float16* hinL = hLbuf + (size_t)(t & 1) * (BB * HID);
    _Float16* houtH = hHbuf + (size_t)((t + 1) & 1) * (BB * HID);
    _Float16* houtL = hLbuf + (size_t)((t + 1) & 1) * (BB * HID);
    f32x4 accM[4], accC[4], accyM, accyC;
#pragma unroll
    for (int r = 0; r < 4; ++r) {
      size_t bi = (size_t)(bD0 + r) * G4 + nt * 16 + l15;
#pragma unroll
      for (int g = 0; g < 4; ++g) { accM[g][r] = bias[bi + (size_t)g * HID]; accC[g][r] = 0.f; }
      accyM[r] = bo; accyC[r] = 0.f;
    }
#pragma unroll 4
    for (int kc = 0; kc < 32; ++kc) {
      f16x8 aH = *(const f16x8*)(hinH + aoff + kc * 32);
      f16x8 aL = *(const f16x8*)(hinL + aoff + kc * 32);
#pragma unroll
      for (int g = 0; g < 4; ++g) {
        f16x8 wH = *(const f16x8*)(WeffH + wrow[g] + kc * 32);
        f16x8 wL = *(const f16x8*)(WeffL + wrow[g] + kc * 32);
        accM[g] = __builtin_amdgcn_mfma_f32_16x16x32_f16(aH, wH, accM[g], 0, 0, 0);
        accC[g] = __builtin_amdgcn_mfma_f32_16x16x32_f16(aL, wH, accC[g], 0, 0, 0);
        accC[g] = __builtin_amdgcn_mfma_f32_16x16x32_f16(aH, wL, accC[g], 0, 0, 0);
      }
      if (doy) {
        f16x8 wy = *(const f16x8*)(Wob + yrow + kc * 32);
        accyM = __builtin_amdgcn_mfma_f32_16x16x32_f16(aH, wy, accyM, 0, 0, 0);
        accyC = __builtin_amdgcn_mfma_f32_16x16x32_f16(aL, wy, accyC, 0, 0, 0);
      }
    }
    // LSTM cell (fp32), write h_{t+1} as f16 hi/lo
#pragma unroll
    for (int r = 0; r < 4; ++r) {
      float zi = accM[0][r] + accC[0][r] * LOINV;
      float zf = accM[1][r] + accC[1][r] * LOINV;
      float zg = accM[2][r] + accC[2][r] * LOINV;
      float zo = accM[3][r] + accC[3][r] * LOINV;
      float ig = fsig(zi);
      float fg = fsig(zf);
      float gg = ftanh_(zg);
      float og = fsig(zo);
      float cn = fg * c[r] + ig * gg;
      c[r] = cn;
      float hn = og * ftanh_(cn);
      _Float16 hi = (_Float16)hn;
      houtH[(size_t)(bD0 + r) * HID + j] = hi;
      houtL[(size_t)(bD0 + r) * HID + j] = (_Float16)((hn - (float)hi) * LOSCALE);
    }
    // y_{t-1} = Wout*h_t + bout, masked store
    if (doy && t > 0) {
      int tb = t - 1;
#pragma unroll
      for (int r = 0; r < 4; ++r) {
        float v = (tb < mylen[r]) ? (accyM[r] + accyC[r] * LOINV) : 0.0f;
        out[((size_t)(bD0 + r) * TLEN + tb) * OUTD + o] = v;
      }
    }
    gridbar(flags, go, (unsigned)(t + 1));
  }
  // final y_{511} = Wout*h_512 + bout  (h_512 lives in half 0)
  if (doy) {
    const _Float16* hinH = hHbuf;
    const _Float16* hinL = hLbuf;
    f32x4 accyM, accyC;
#pragma unroll
    for (int r = 0; r < 4; ++r) { accyM[r] = bo; accyC[r] = 0.f; }
#pragma unroll 4
    for (int kc = 0; kc < 32; ++kc) {
      f16x8 aH = *(const f16x8*)(hinH + aoff + kc * 32);
      f16x8 aL = *(const f16x8*)(hinL + aoff + kc * 32);
      f16x8 wy = *(const f16x8*)(Wob + yrow + kc * 32);
      accyM = __builtin_amdgcn_mfma_f32_16x16x32_f16(aH, wy, accyM, 0, 0, 0);
      accyC = __builtin_amdgcn_mfma_f32_16x16x32_f16(aL, wy, accyC, 0, 0, 0);
    }
#pragma unroll
    for (int r = 0; r < 4; ++r) {
      float v = ((TLEN - 1) < mylen[r]) ? (accyM[r] + accyC[r] * LOINV) : 0.0f;
      out[((size_t)(bD0 + r) * TLEN + (TLEN - 1)) * OUTD + o] = v;
    }
  }
}

// ---------------- host ----------------

extern "C" void kernel_launch(void* const* d_in, const int* in_sizes, int n_in,
                              void* d_out, int out_size, void* d_ws, size_t ws_size,
                              hipStream_t stream)
{
  const float* lat  = (const float*)d_in[0];
  const float* cond = (const float*)d_in[1];
  const int*   len  = (const int*)d_in[2];
  const float* Wh   = (const float*)d_in[3];
  const float* bh   = (const float*)d_in[4];
  const float* Wc   = (const float*)d_in[5];
  const float* bc   = (const float*)d_in[6];
  const float* Ws   = (const float*)d_in[7];
  const float* bs   = (const float*)d_in[8];
  const float* Wih  = (const float*)d_in[9];
  const float* Whh  = (const float*)d_in[10];
  const float* bih  = (const float*)d_in[11];
  const float* bhh  = (const float*)d_in[12];
  const float* Wout = (const float*)d_in[13];
  const float* bout = (const float*)d_in[14];
  float* out = (float*)d_out;

  char* ws = (char*)d_ws;
  size_t off = 0;
  auto alloc = [&](size_t bytes) -> void* {
    void* p = ws + off;
    off += (bytes + 255) & ~(size_t)255;
    return p;
  };
  _Float16* hH    = (_Float16*)alloc((size_t)2 * BB * HID * 2);
  _Float16* hL    = (_Float16*)alloc((size_t)2 * BB * HID * 2);
  float*    c0    = (float*)alloc((size_t)BB * HID * 4);
  float*    h0    = (float*)alloc((size_t)BB * HID * 4);
  float*    x0    = (float*)alloc((size_t)BB * OUTD * 4);
  float*    dxy   = (float*)alloc((size_t)BB * OUTD * 4);
  _Float16* Wob   = (_Float16*)alloc((size_t)OUTD * HID * 2);
  _Float16* WeffH = (_Float16*)alloc((size_t)G4 * HID * 2);
  _Float16* WeffL = (_Float16*)alloc((size_t)G4 * HID * 2);
  float*    biasR = (float*)alloc((size_t)BB * G4 * 4);
  float*    biasS = (float*)alloc((size_t)BB * G4 * 4);
  unsigned* flags = (unsigned*)alloc(256 * 32 * 4);
  unsigned* go    = (unsigned*)alloc(256);
  if (off > ws_size) return;   // insufficient workspace (will show as absmax fail)

  // barrier state must be clean every call (0xAA poison / stale generations)
  hipMemsetAsync(flags, 0, 256 * 32 * 4 + 256, stream);

  prep_init<<<dim3(9, 32),   256, 0, stream>>>(lat, Wh, bh, Wc, bc, Ws, bs, h0, hH, hL, c0, x0);
  prep_weff<<<dim3(4, 256),  256, 0, stream>>>(Whh, Wih, Wout, WeffH, WeffL);
  prep_wob <<<dim3(512),     256, 0, stream>>>(Wout, Wob);
  prep_d   <<<dim3(128),     256, 0, stream>>>(h0, Wout, bout, x0, dxy);
  prep_bias<<<dim3(16, 32),  256, 0, stream>>>(cond, Wih, bih, bhh, bout, dxy, biasR, biasS);
  lstm_main<<<dim3(256),     256, 0, stream>>>(hH, hL, c0, biasR, biasS, WeffH, WeffL, Wob, bout, len, out, flags, go);
}

// Round 3
// 23785.413 us; speedup vs baseline: 1.9080x; 1.9080x over previous
//
#include <hip/hip_runtime.h>

#define BB   256
#define LAT  256
#define CND  64
#define HID  1024
#define OUTD 128
#define TLEN 512
#define GIN  192
#define G4   4096

typedef _Float16 f16x8 __attribute__((ext_vector_type(8)));
typedef float    f32x4 __attribute__((ext_vector_type(4)));

#define LOSCALE 2048.0f
#define LOINV   (1.0f / 2048.0f)

__device__ __forceinline__ float fsig(float x) {
  return 1.0f / (1.0f + exp2f(-1.4426950408889634f * x));
}
__device__ __forceinline__ float ftanh_(float x) {
  return 2.0f / (1.0f + exp2f(2.8853900817779268f * (-x))) - 1.0f;
}

// ---- device-coherent (MALL) access helpers: per-instruction bypass, no cache-wide ops ----
__device__ __forceinline__ f16x8 ldg_sc(const _Float16* p) {
  f16x8 v;
  asm volatile("global_load_dwordx4 %0, %1, off sc0 sc1" : "=v"(v) : "v"(p));
  return v;
}
__device__ __forceinline__ void stg_sc_h(_Float16* p, _Float16 v) {
  unsigned u = (unsigned)__builtin_bit_cast(unsigned short, v);
  asm volatile("global_store_short %0, %1, off sc0 sc1" :: "v"(p), "v"(u) : "memory");
}
__device__ __forceinline__ void stg_sc_f(float* p, float v) {
  asm volatile("global_store_dword %0, %1, off sc0 sc1" :: "v"(p), "v"(v) : "memory");
}
#define S_WAITVM(N) asm volatile("s_waitcnt vmcnt(" #N ")" ::: "memory")
#define LDSBAR() { asm volatile("s_waitcnt lgkmcnt(0)" ::: "memory"); __builtin_amdgcn_s_barrier(); }

// ---------------- prep kernels (unchanged from round 2) ----------------

__global__ void prep_init(const float* __restrict__ lat,
                          const float* __restrict__ Wh, const float* __restrict__ bh,
                          const float* __restrict__ Wc, const float* __restrict__ bc,
                          const float* __restrict__ Ws, const float* __restrict__ bs,
                          float* __restrict__ h0, _Float16* __restrict__ hH, _Float16* __restrict__ hL,
                          float* __restrict__ c0, float* __restrict__ x0)
{
  __shared__ float lat_s[8][LAT];
  int tid = threadIdx.x;
  int b0 = blockIdx.y * 8;
  for (int bb = 0; bb < 8; ++bb)
    lat_s[bb][tid] = lat[(size_t)(b0 + bb) * LAT + tid];
  __syncthreads();
  int col = blockIdx.x * 256 + tid;
  if (col >= 2 * HID + OUTD) return;
  const float* wr; float bias; int kind; int cc;
  if (col < HID)            { cc = col;           wr = Wh + (size_t)cc * LAT; bias = bh[cc]; kind = 0; }
  else if (col < 2 * HID)   { cc = col - HID;     wr = Wc + (size_t)cc * LAT; bias = bc[cc]; kind = 1; }
  else                      { cc = col - 2 * HID; wr = Ws + (size_t)cc * LAT; bias = bs[cc]; kind = 2; }
  float acc[8];
#pragma unroll
  for (int bb = 0; bb < 8; ++bb) acc[bb] = bias;
  for (int k = 0; k < LAT; ++k) {
    float wv = wr[k];
#pragma unroll
    for (int bb = 0; bb < 8; ++bb) acc[bb] += lat_s[bb][k] * wv;
  }
  for (int bb = 0; bb < 8; ++bb) {
    int b = b0 + bb;
    if (kind == 0) {
      float v = acc[bb];
      h0[(size_t)b*HID + cc] = v;
      _Float16 hi = (_Float16)v;
      hH[(size_t)b*HID + cc] = hi;
      hL[(size_t)b*HID + cc] = (_Float16)((v - (float)hi) * LOSCALE);
    }
    else if (kind == 1) { c0[(size_t)b*HID + cc] = acc[bb]; }
    else                { x0[(size_t)b*OUTD + cc] = acc[bb]; }
  }
}

__global__ void prep_d(const float* __restrict__ h0, const float* __restrict__ Wout,
                       const float* __restrict__ bout, const float* __restrict__ x0,
                       float* __restrict__ d)
{
  int t = blockIdx.x * 256 + threadIdx.x;
  int b = t >> 7, o = t & 127;
  const float* wr = Wout + (size_t)o * HID;
  const float* hr = h0 + (size_t)b * HID;
  float acc = bout[o];
  for (int k = 0; k < HID; ++k) acc += hr[k] * wr[k];
  d[t] = x0[t] - acc;
}

__global__ void prep_weff(const float* __restrict__ Whh, const float* __restrict__ Wih,
                          const float* __restrict__ Wout,
                          _Float16* __restrict__ WeffH, _Float16* __restrict__ WeffL)
{
  int k = blockIdx.x * 256 + threadIdx.x;
  int n0 = blockIdx.y * 16;
  float acc[16];
#pragma unroll
  for (int nn = 0; nn < 16; ++nn) acc[nn] = Whh[(size_t)(n0 + nn) * HID + k];
  for (int j = 0; j < OUTD; ++j) {
    float wo = Wout[(size_t)j * HID + k];
#pragma unroll
    for (int nn = 0; nn < 16; ++nn) acc[nn] += Wih[(size_t)(n0 + nn) * GIN + j] * wo;
  }
#pragma unroll
  for (int nn = 0; nn < 16; ++nn) {
    size_t idx = (size_t)(n0 + nn) * HID + k;
    float wv = acc[nn];
    _Float16 hi = (_Float16)wv;
    WeffH[idx] = hi;
    WeffL[idx] = (_Float16)((wv - (float)hi) * LOSCALE);
  }
}

__global__ void prep_wob(const float* __restrict__ Wout, _Float16* __restrict__ Wob) {
  int t = blockIdx.x * 256 + threadIdx.x;
  Wob[t] = (_Float16)Wout[t];
}

__global__ void prep_bias(const float* __restrict__ cond, const float* __restrict__ Wih,
                          const float* __restrict__ bih, const float* __restrict__ bhh,
                          const float* __restrict__ bout, const float* __restrict__ d,
                          float* __restrict__ biasR, float* __restrict__ biasS)
{
  __shared__ float cond_s[8][CND];
  __shared__ float d_s[8][OUTD];
  int tid = threadIdx.x;
  int b0 = blockIdx.y * 8;
  for (int qq = 0; qq < 2; ++qq) {
    int idx = qq * 256 + tid;
    cond_s[idx >> 6][idx & 63] = cond[(size_t)(b0 + (idx >> 6)) * CND + (idx & 63)];
  }
  for (int qq = 0; qq < 4; ++qq) {
    int idx = qq * 256 + tid;
    d_s[idx >> 7][idx & 127] = d[(size_t)(b0 + (idx >> 7)) * OUTD + (idx & 127)];
  }
  __syncthreads();
  int n = blockIdx.x * 256 + tid;
  const float* wi = Wih + (size_t)n * GIN;
  float base = bih[n] + bhh[n];
  float aR[8], aS[8];
#pragma unroll
  for (int bb = 0; bb < 8; ++bb) { aR[bb] = 0.f; aS[bb] = 0.f; }
  for (int c = 0; c < CND; ++c) {
    float wv = wi[OUTD + c];
#pragma unroll
    for (int bb = 0; bb < 8; ++bb) aR[bb] += cond_s[bb][c] * wv;
  }
  for (int o = 0; o < OUTD; ++o) {
    float wv = wi[o];
    float bo = bout[o];
#pragma unroll
    for (int bb = 0; bb < 8; ++bb) { aR[bb] += bo * wv; aS[bb] += d_s[bb][o] * wv; }
  }
  for (int bb = 0; bb < 8; ++bb) {
    size_t idx = (size_t)(b0 + bb) * G4 + n;
    biasR[idx] = base + aR[bb];
    biasS[idx] = base + aR[bb] + aS[bb];
  }
}

// ---------------- global barrier: relaxed counter at MALL, no cache-wide ops ----------------

__device__ __forceinline__ void barrier_all(unsigned* ctr, unsigned target) {
  asm volatile("s_waitcnt vmcnt(0)" ::: "memory");   // my sc1-stores are at MALL
  __syncthreads();
  if (threadIdx.x == 0) {
    __hip_atomic_fetch_add(ctr, 1u, __ATOMIC_RELAXED, __HIP_MEMORY_SCOPE_AGENT);
    long guard = 0;
    while (__hip_atomic_load(ctr, __ATOMIC_RELAXED, __HIP_MEMORY_SCOPE_AGENT) < target) {
      if (++guard > 50000L) break;                   // fail-fast, don't hang
      __builtin_amdgcn_s_sleep(1);
    }
  }
  __syncthreads();
  asm volatile("" ::: "memory");
}

// ---------------- main persistent kernel ----------------

__global__ __launch_bounds__(256, 1)
void lstm_main(_Float16* hHbuf, _Float16* hLbuf, const float* __restrict__ c0g,
               const float* __restrict__ biasR, const float* __restrict__ biasS,
               const _Float16* __restrict__ WeffH, const _Float16* __restrict__ WeffL,
               const _Float16* __restrict__ Wob, const float* __restrict__ bout,
               const int* __restrict__ len, float* __restrict__ out, unsigned* ctr)
{
  __shared__ __align__(16) char lds[65536];   // 2 buffers x (hi 16K + lo 16K)
  const int wg = blockIdx.x;                  // 256 wgs
  const int xcd = wg & 7, slot = wg >> 3;
  const int q = slot >> 2, mt = slot & 3;
  const int nt = q * 8 + xcd;                 // W-slice stays in this XCD's L2
  const int tid = threadIdx.x;
  const int w = tid >> 6, lane = tid & 63;
  const int l15 = lane & 15, lh = lane >> 4;
  const int rowA = w * 16 + l15;              // local A row 0..63
  const int rowsw = (rowA & 7) << 4;
  const int bA = mt * 64 + rowA;              // global A row
  const int bD0 = mt * 64 + w * 16 + lh * 4;  // C/D row base (+r)
  const int j = nt * 16 + l15;

  const bool doy = (nt < 8);
  const int oy = doy ? nt * 16 + l15 : 0;
  const float bo = doy ? bout[oy] : 0.0f;

  // per-thread weight base pointers (stay cached in L1/L2; never invalidated)
  const _Float16* wbH[4];
  const _Float16* wbL[4];
#pragma unroll
  for (int g = 0; g < 4; ++g) {
    size_t r0 = (size_t)(g * HID + nt * 16 + l15) * HID + lh * 8;
    wbH[g] = WeffH + r0;
    wbL[g] = WeffL + r0;
  }
  const _Float16* wbY = Wob + (size_t)oy * HID + lh * 8;

  float c[4];
  int mylen[4];
  float biasRv[16];
#pragma unroll
  for (int r = 0; r < 4; ++r) {
    c[r] = c0g[(size_t)(bD0 + r) * HID + j];
    mylen[r] = len[bD0 + r];
    size_t bi = (size_t)(bD0 + r) * G4 + nt * 16 + l15;
#pragma unroll
    for (int g = 0; g < 4; ++g) biasRv[r * 4 + g] = biasR[bi + (size_t)g * HID];
  }

  f32x4 accM[4], accC[4], accyM, accyC;
  f16x8 sA[8], sB[8], sC[8];
  const _Float16 *curH, *curL;

  auto issue = [&](f16x8* dst, int kchunk) {
#pragma unroll
    for (int i = 0; i < 8; ++i) {
      int s = i * 256 + tid;
      int p = s >> 10, r = (s >> 4) & 63, c16 = s & 15;
      const _Float16* src = (p ? curL : curH) + (size_t)(mt * 64 + r) * HID + kchunk * 128 + c16 * 8;
      dst[i] = ldg_sc(src);
    }
  };
  auto dswr = [&](const f16x8* sreg, int bufsel) {
    char* b = lds + bufsel * 32768;
#pragma unroll
    for (int i = 0; i < 8; ++i) {
      int s = i * 256 + tid;
      int p = s >> 10, r = (s >> 4) & 63, c16 = s & 15;
      *(f16x8*)(b + p * 16384 + r * 256 + ((c16 * 16) ^ ((r & 7) << 4))) = sreg[i];
    }
  };
  auto compchunk = [&](int kchunk, int bufsel) {
    const char* b = lds + bufsel * 32768;
#pragma unroll
    for (int kc = 0; kc < 4; ++kc) {
      int cb = (kc * 64 + lh * 16) ^ rowsw;
      f16x8 aH = *(const f16x8*)(b + rowA * 256 + cb);
      f16x8 aL = *(const f16x8*)(b + 16384 + rowA * 256 + cb);
      int wo = kchunk * 128 + kc * 32;
#pragma unroll
      for (int g = 0; g < 4; ++g) {
        f16x8 wH = *(const f16x8*)(wbH[g] + wo);
        f16x8 wL = *(const f16x8*)(wbL[g] + wo);
        accM[g] = __builtin_amdgcn_mfma_f32_16x16x32_f16(aH, wH, accM[g], 0, 0, 0);
        accC[g] = __builtin_amdgcn_mfma_f32_16x16x32_f16(aL, wH, accC[g], 0, 0, 0);
        accC[g] = __builtin_amdgcn_mfma_f32_16x16x32_f16(aH, wL, accC[g], 0, 0, 0);
      }
      if (doy) {
        f16x8 wy = *(const f16x8*)(wbY + wo);
        accyM = __builtin_amdgcn_mfma_f32_16x16x32_f16(aH, wy, accyM, 0, 0, 0);
        accyC = __builtin_amdgcn_mfma_f32_16x16x32_f16(aL, wy, accyC, 0, 0, 0);
      }
    }
  };

  for (int t = 0; t < TLEN; ++t) {
    curH = hHbuf + (size_t)(t & 1) * (BB * HID);
    curL = hLbuf + (size_t)(t & 1) * (BB * HID);
    _Float16* houtH = hHbuf + (size_t)((t + 1) & 1) * (BB * HID);
    _Float16* houtL = hLbuf + (size_t)((t + 1) & 1) * (BB * HID);

    // start the staging pipeline ASAP (3 chunks deep)
    issue(sA, 0); issue(sB, 1); issue(sC, 2);

    // accumulator init from registers (biasS only at t==0)
#pragma unroll
    for (int r = 0; r < 4; ++r) {
#pragma unroll
      for (int g = 0; g < 4; ++g) { accM[g][r] = biasRv[r * 4 + g]; accC[g][r] = 0.f; }
      accyM[r] = bo; accyC[r] = 0.f;
    }
    if (t == 0) {
#pragma unroll
      for (int r = 0; r < 4; ++r) {
        size_t bi = (size_t)(bD0 + r) * G4 + nt * 16 + l15;
#pragma unroll
        for (int g = 0; g < 4; ++g) accM[g][r] = biasS[bi + (size_t)g * HID];
      }
    }

    // 8 chunks, counted-vmcnt pipeline, raw barriers (no vmcnt drain)
    S_WAITVM(16); dswr(sA, 0); LDSBAR(); issue(sA, 3); compchunk(0, 0);
    S_WAITVM(16); dswr(sB, 1); LDSBAR(); issue(sB, 4); compchunk(1, 1);
    S_WAITVM(16); dswr(sC, 0); LDSBAR(); issue(sC, 5); compchunk(2, 0);
    S_WAITVM(16); dswr(sA, 1); LDSBAR(); issue(sA, 6); compchunk(3, 1);
    S_WAITVM(16); dswr(sB, 0); LDSBAR(); issue(sB, 7); compchunk(4, 0);
    S_WAITVM(16); dswr(sC, 1); LDSBAR();               compchunk(5, 1);
    S_WAITVM(8);  dswr(sA, 0); LDSBAR();               compchunk(6, 0);
    S_WAITVM(0);  dswr(sB, 1); LDSBAR();               compchunk(7, 1);

    // LSTM cell (fp32), h_{t+1} hi/lo via device-coherent stores
#pragma unroll
    for (int r = 0; r < 4; ++r) {
      float zi = accM[0][r] + accC[0][r] * LOINV;
      float zf = accM[1][r] + accC[1][r] * LOINV;
      float zg = accM[2][r] + accC[2][r] * LOINV;
      float zo = accM[3][r] + accC[3][r] * LOINV;
      float ig = fsig(zi);
      float fg = fsig(zf);
      float gg = ftanh_(zg);
      float og = fsig(zo);
      float cn = fg * c[r] + ig * gg;
      c[r] = cn;
      float hn = og * ftanh_(cn);
      _Float16 hi = (_Float16)hn;
      _Float16 lo = (_Float16)((hn - (float)hi) * LOSCALE);
      stg_sc_h(houtH + (size_t)(bD0 + r) * HID + j, hi);
      stg_sc_h(houtL + (size_t)(bD0 + r) * HID + j, lo);
    }
    // y_{t-1} = Wout*h_t + bout
    if (doy && t > 0) {
      int tb = t - 1;
#pragma unroll
      for (int r = 0; r < 4; ++r) {
        float v = (tb < mylen[r]) ? (accyM[r] + accyC[r] * LOINV) : 0.0f;
        stg_sc_f(out + ((size_t)(bD0 + r) * TLEN + tb) * OUTD + oy, v);
      }
    }
    barrier_all(ctr, 256u * (unsigned)(t + 1));
  }

  // epilogue: y_{511} = Wout*h_512 + bout   (h_512 in parity-0 buffers)
  if (doy) {
    const _Float16* hinH = hHbuf;
    const _Float16* hinL = hLbuf;
    f32x4 aM, aC;
#pragma unroll
    for (int r = 0; r < 4; ++r) { aM[r] = bo; aC[r] = 0.f; }
    for (int k8 = 0; k8 < 8; ++k8) {
      f16x8 aH[4], aL[4];
#pragma unroll
      for (int qq = 0; qq < 4; ++qq) {
        aH[qq] = ldg_sc(hinH + (size_t)bA * HID + k8 * 128 + qq * 32 + lh * 8);
        aL[qq] = ldg_sc(hinL + (size_t)bA * HID + k8 * 128 + qq * 32 + lh * 8);
      }
      S_WAITVM(0);
#pragma unroll
      for (int qq = 0; qq < 4; ++qq) {
        int wo = k8 * 128 + qq * 32;
        f16x8 wy = *(const f16x8*)(wbY + wo);
        aM = __builtin_amdgcn_mfma_f32_16x16x32_f16(aH[qq], wy, aM, 0, 0, 0);
        aC = __builtin_amdgcn_mfma_f32_16x16x32_f16(aL[qq], wy, aC, 0, 0, 0);
      }
    }
#pragma unroll
    for (int r = 0; r < 4; ++r) {
      float v = ((TLEN - 1) < mylen[r]) ? (aM[r] + aC[r] * LOINV) : 0.0f;
      stg_sc_f(out + ((size_t)(bD0 + r) * TLEN + (TLEN - 1)) * OUTD + oy, v);
    }
  }
}

// ---------------- host ----------------

extern "C" void kernel_launch(void* const* d_in, const int* in_sizes, int n_in,
                              void* d_out, int out_size, void* d_ws, size_t ws_size,
                              hipStream_t stream)
{
  const float* lat  = (const float*)d_in[0];
  const float* cond = (const float*)d_in[1];
  const int*   len  = (const int*)d_in[2];
  const float* Wh   = (const float*)d_in[3];
  const float* bh   = (const float*)d_in[4];
  const float* Wc   = (const float*)d_in[5];
  const float* bc   = (const float*)d_in[6];
  const float* Ws   = (const float*)d_in[7];
  const float* bs   = (const float*)d_in[8];
  const float* Wih  = (const float*)d_in[9];
  const float* Whh  = (const float*)d_in[10];
  const float* bih  = (const float*)d_in[11];
  const float* bhh  = (const float*)d_in[12];
  const float* Wout = (const float*)d_in[13];
  const float* bout = (const float*)d_in[14];
  float* out = (float*)d_out;

  char* ws = (char*)d_ws;
  size_t off = 0;
  auto alloc = [&](size_t bytes) -> void* {
    void* p = ws + off;
    off += (bytes + 255) & ~(size_t)255;
    return p;
  };
  _Float16* hH    = (_Float16*)alloc((size_t)2 * BB * HID * 2);
  _Float16* hL    = (_Float16*)alloc((size_t)2 * BB * HID * 2);
  float*    c0    = (float*)alloc((size_t)BB * HID * 4);
  float*    h0    = (float*)alloc((size_t)BB * HID * 4);
  float*    x0    = (float*)alloc((size_t)BB * OUTD * 4);
  float*    dxy   = (float*)alloc((size_t)BB * OUTD * 4);
  _Float16* Wob   = (_Float16*)alloc((size_t)OUTD * HID * 2);
  _Float16* WeffH = (_Float16*)alloc((size_t)G4 * HID * 2);
  _Float16* WeffL = (_Float16*)alloc((size_t)G4 * HID * 2);
  float*    biasR = (float*)alloc((size_t)BB * G4 * 4);
  float*    biasS = (float*)alloc((size_t)BB * G4 * 4);
  unsigned* ctr   = (unsigned*)alloc(256);
  if (off > ws_size) return;

  hipMemsetAsync(ctr, 0, 256, stream);

  prep_init<<<dim3(9, 32),   256, 0, stream>>>(lat, Wh, bh, Wc, bc, Ws, bs, h0, hH, hL, c0, x0);
  prep_weff<<<dim3(4, 256),  256, 0, stream>>>(Whh, Wih, Wout, WeffH, WeffL);
  prep_wob <<<dim3(512),     256, 0, stream>>>(Wout, Wob);
  prep_d   <<<dim3(128),     256, 0, stream>>>(h0, Wout, bout, x0, dxy);
  prep_bias<<<dim3(16, 32),  256, 0, stream>>>(cond, Wih, bih, bhh, bout, dxy, biasR, biasS);
  lstm_main<<<dim3(256),     256, 0, stream>>>(hH, hL, c0, biasR, biasS, WeffH, WeffL, Wob, bout, len, out, ctr);
}

// Round 4
// 21170.784 us; speedup vs baseline: 2.1436x; 1.1235x over previous
//
#include <hip/hip_runtime.h>

#define BB   256
#define LAT  256
#define CND  64
#define HID  1024
#define OUTD 128
#define TLEN 512
#define GIN  192
#define G4   4096

typedef _Float16 f16x8 __attribute__((ext_vector_type(8)));
typedef float    f32x4 __attribute__((ext_vector_type(4)));
typedef unsigned u32x4 __attribute__((ext_vector_type(4)));
typedef unsigned u32x2 __attribute__((ext_vector_type(2)));

#define LOSCALE 2048.0f
#define LOINV   (1.0f / 2048.0f)

#define MFMA16(A,B,C) __builtin_amdgcn_mfma_f32_16x16x32_f16((A),(B),(C),0,0,0)

__device__ __forceinline__ float fsig(float x) {
  return 1.0f / (1.0f + exp2f(-1.4426950408889634f * x));
}
__device__ __forceinline__ float ftanh_(float x) {
  return 2.0f / (1.0f + exp2f(2.8853900817779268f * (-x))) - 1.0f;
}

// ---- device-coherent (MALL) access: per-instruction bypass, no cache-wide ops ----
__device__ __forceinline__ u32x4 ldg_sc_u4(const void* p) {
  u32x4 v;
  asm volatile("global_load_dwordx4 %0, %1, off sc0 sc1" : "=v"(v) : "v"(p));
  return v;
}
__device__ __forceinline__ void stg_sc_u32(void* p, unsigned v) {
  asm volatile("global_store_dword %0, %1, off sc0 sc1" :: "v"(p), "v"(v) : "memory");
}
__device__ __forceinline__ void stg_sc_f32(void* p, float v) {
  asm volatile("global_store_dword %0, %1, off sc0 sc1" :: "v"(p), "v"(v) : "memory");
}

template<int N> __device__ __forceinline__ void waitvm() {
  if constexpr (N == 24)      asm volatile("s_waitcnt vmcnt(24)" ::: "memory");
  else if constexpr (N == 16) asm volatile("s_waitcnt vmcnt(16)" ::: "memory");
  else if constexpr (N == 8)  asm volatile("s_waitcnt vmcnt(8)"  ::: "memory");
  else                        asm volatile("s_waitcnt vmcnt(0)"  ::: "memory");
  __builtin_amdgcn_sched_barrier(0);
}
#define LDSBAR() { asm volatile("s_waitcnt lgkmcnt(0)" ::: "memory"); \
                   __builtin_amdgcn_s_barrier(); \
                   __builtin_amdgcn_sched_barrier(0); }

template<int N> struct IC { static constexpr int v = N; };

// ---------------- prep kernels ----------------

__global__ void prep_init(const float* __restrict__ lat,
                          const float* __restrict__ Wh, const float* __restrict__ bh,
                          const float* __restrict__ Wc, const float* __restrict__ bc,
                          const float* __restrict__ Ws, const float* __restrict__ bs,
                          float* __restrict__ h0, unsigned* __restrict__ hI,
                          float* __restrict__ c0, float* __restrict__ x0)
{
  __shared__ float lat_s[8][LAT];
  int tid = threadIdx.x;
  int b0 = blockIdx.y * 8;
  for (int bb = 0; bb < 8; ++bb)
    lat_s[bb][tid] = lat[(size_t)(b0 + bb) * LAT + tid];
  __syncthreads();
  int col = blockIdx.x * 256 + tid;
  if (col >= 2 * HID + OUTD) return;
  const float* wr; float bias; int kind; int cc;
  if (col < HID)            { cc = col;           wr = Wh + (size_t)cc * LAT; bias = bh[cc]; kind = 0; }
  else if (col < 2 * HID)   { cc = col - HID;     wr = Wc + (size_t)cc * LAT; bias = bc[cc]; kind = 1; }
  else                      { cc = col - 2 * HID; wr = Ws + (size_t)cc * LAT; bias = bs[cc]; kind = 2; }
  float acc[8];
#pragma unroll
  for (int bb = 0; bb < 8; ++bb) acc[bb] = bias;
  for (int k = 0; k < LAT; ++k) {
    float wv = wr[k];
#pragma unroll
    for (int bb = 0; bb < 8; ++bb) acc[bb] += lat_s[bb][k] * wv;
  }
  for (int bb = 0; bb < 8; ++bb) {
    int b = b0 + bb;
    if (kind == 0) {
      float v = acc[bb];
      h0[(size_t)b*HID + cc] = v;
      _Float16 hi = (_Float16)v;
      _Float16 lo = (_Float16)((v - (float)hi) * LOSCALE);
      unsigned hu = (unsigned)__builtin_bit_cast(unsigned short, hi)
                  | ((unsigned)__builtin_bit_cast(unsigned short, lo) << 16);
      hI[(size_t)b*HID + cc] = hu;
    }
    else if (kind == 1) { c0[(size_t)b*HID + cc] = acc[bb]; }
    else                { x0[(size_t)b*OUTD + cc] = acc[bb]; }
  }
}

__global__ void prep_d(const float* __restrict__ h0, const float* __restrict__ Wout,
                       const float* __restrict__ bout, const float* __restrict__ x0,
                       float* __restrict__ d)
{
  int t = blockIdx.x * 256 + threadIdx.x;
  int b = t >> 7, o = t & 127;
  const float* wr = Wout + (size_t)o * HID;
  const float* hr = h0 + (size_t)b * HID;
  float acc = bout[o];
  for (int k = 0; k < HID; ++k) acc += hr[k] * wr[k];
  d[t] = x0[t] - acc;
}

__global__ void prep_weff(const float* __restrict__ Whh, const float* __restrict__ Wih,
                          const float* __restrict__ Wout,
                          _Float16* __restrict__ WeffH, _Float16* __restrict__ WeffL)
{
  int k = blockIdx.x * 256 + threadIdx.x;
  int n0 = blockIdx.y * 16;
  float acc[16];
#pragma unroll
  for (int nn = 0; nn < 16; ++nn) acc[nn] = Whh[(size_t)(n0 + nn) * HID + k];
  for (int j = 0; j < OUTD; ++j) {
    float wo = Wout[(size_t)j * HID + k];
#pragma unroll
    for (int nn = 0; nn < 16; ++nn) acc[nn] += Wih[(size_t)(n0 + nn) * GIN + j] * wo;
  }
#pragma unroll
  for (int nn = 0; nn < 16; ++nn) {
    size_t idx = (size_t)(n0 + nn) * HID + k;
    float wv = acc[nn];
    _Float16 hi = (_Float16)wv;
    WeffH[idx] = hi;
    WeffL[idx] = (_Float16)((wv - (float)hi) * LOSCALE);
  }
}

__global__ void prep_wob(const float* __restrict__ Wout, _Float16* __restrict__ Wob) {
  int t = blockIdx.x * 256 + threadIdx.x;
  Wob[t] = (_Float16)Wout[t];
}

__global__ void prep_bias(const float* __restrict__ cond, const float* __restrict__ Wih,
                          const float* __restrict__ bih, const float* __restrict__ bhh,
                          const float* __restrict__ bout, const float* __restrict__ d,
                          float* __restrict__ biasR, float* __restrict__ biasS)
{
  __shared__ float cond_s[8][CND];
  __shared__ float d_s[8][OUTD];
  int tid = threadIdx.x;
  int b0 = blockIdx.y * 8;
  for (int qq = 0; qq < 2; ++qq) {
    int idx = qq * 256 + tid;
    cond_s[idx >> 6][idx & 63] = cond[(size_t)(b0 + (idx >> 6)) * CND + (idx & 63)];
  }
  for (int qq = 0; qq < 4; ++qq) {
    int idx = qq * 256 + tid;
    d_s[idx >> 7][idx & 127] = d[(size_t)(b0 + (idx >> 7)) * OUTD + (idx & 127)];
  }
  __syncthreads();
  int n = blockIdx.x * 256 + tid;
  const float* wi = Wih + (size_t)n * GIN;
  float base = bih[n] + bhh[n];
  float aR[8], aS[8];
#pragma unroll
  for (int bb = 0; bb < 8; ++bb) { aR[bb] = 0.f; aS[bb] = 0.f; }
  for (int c = 0; c < CND; ++c) {
    float wv = wi[OUTD + c];
#pragma unroll
    for (int bb = 0; bb < 8; ++bb) aR[bb] += cond_s[bb][c] * wv;
  }
  for (int o = 0; o < OUTD; ++o) {
    float wv = wi[o];
    float bo = bout[o];
#pragma unroll
    for (int bb = 0; bb < 8; ++bb) { aR[bb] += bo * wv; aS[bb] += d_s[bb][o] * wv; }
  }
  for (int bb = 0; bb < 8; ++bb) {
    size_t idx = (size_t)(b0 + bb) * G4 + n;
    biasR[idx] = base + aR[bb];
    biasS[idx] = base + aR[bb] + aS[bb];
  }
}

// ---------------- main persistent kernel ----------------
// Grid: 256 wgs = 4 mt (64-batch tiles) x 64 nt (16 gate-cols). Per-mt barrier only.

__global__ __launch_bounds__(256, 1)
void lstm_main(unsigned* hI, const float* __restrict__ c0g,
               const float* __restrict__ biasR, const float* __restrict__ biasS,
               const _Float16* __restrict__ WeffH, const _Float16* __restrict__ WeffL,
               const _Float16* __restrict__ Wob, const float* __restrict__ bout,
               const int* __restrict__ len, float* __restrict__ out, unsigned* bar)
{
  __shared__ __align__(16) char lds[69632];   // 2 bufs x (H 17408 + L 17408), row stride 272
  const int wg = blockIdx.x;
  const int xcd = wg & 7, slot = wg >> 3;
  const int mt = slot & 3, q = slot >> 2;
  const int nt = q * 8 + xcd;                 // W-slice stays in this XCD's L2
  const int tid = threadIdx.x;
  const int w = tid >> 6, lane = tid & 63;
  const int l15 = lane & 15, lh = lane >> 4;
  const int rowA = w * 16 + l15;
  const int bD0 = mt * 64 + w * 16 + lh * 4;
  const int j = nt * 16 + l15;
  const bool doy = (nt < 8);
  const int oy = doy ? nt * 16 + l15 : 0;
  const float bo = doy ? bout[oy] : 0.0f;

  // weight base pointers (cached loads; never invalidated)
  const char* wbH[4]; const char* wbL[4];
#pragma unroll
  for (int g = 0; g < 4; ++g) {
    size_t r0 = ((size_t)(g * HID + nt * 16 + l15)) * HID + lh * 8;
    wbH[g] = (const char*)(WeffH + r0);
    wbL[g] = (const char*)(WeffL + r0);
  }
  const char* wbY = (const char*)(Wob + (size_t)oy * HID + lh * 8);

  float c[4]; int mylen[4]; float biasRv[16];
#pragma unroll
  for (int r = 0; r < 4; ++r) {
    c[r] = c0g[(size_t)(bD0 + r) * HID + j];
    mylen[r] = len[bD0 + r];
    size_t bi = (size_t)(bD0 + r) * G4 + nt * 16 + l15;
#pragma unroll
    for (int g = 0; g < 4; ++g) biasRv[r * 4 + g] = biasR[bi + (size_t)g * HID];
  }

  // per-thread chunk-load bases (slot s = i*256+tid -> row s>>5, dword-quad s&31)
  unsigned* cb0[8];
  int rc8[8];
#pragma unroll
  for (int i = 0; i < 8; ++i) {
    int s = i * 256 + tid;
    int r = s >> 5, cc = s & 31;
    cb0[i] = hI + ((size_t)(mt * 64 + r) * 1024 + cc * 4);
    rc8[i] = r * 272 + cc * 8;
  }
  const int rdoff = rowA * 272 + lh * 16;
  unsigned* hb0[4];
#pragma unroll
  for (int r = 0; r < 4; ++r) hb0[r] = hI + ((size_t)(bD0 + r) * 1024 + j);

  unsigned* const myarr = bar + (size_t)(mt * 8 + xcd) * 64;   // 256B-spaced lines

  f32x4 accM[4], accC[4], accyM, accyC;
  u32x4 pfb[4][8];

  for (int t = 0; t < TLEN; ++t) {
    const size_t parin  = (size_t)(t & 1) * (BB * HID);
    const size_t parout = (size_t)((t + 1) & 1) * (BB * HID);

    auto issue = [&](auto Kc) {
      constexpr int K = decltype(Kc)::v;
#pragma unroll
      for (int i = 0; i < 8; ++i)
        pfb[K & 3][i] = ldg_sc_u4((const char*)(cb0[i] + parin) + K * 512);
    };
    auto dswr = [&](auto Kc) {
      constexpr int K = decltype(Kc)::v;
      char* Bb = lds + (K & 1) * 34816;
#pragma unroll
      for (int i = 0; i < 8; ++i) {
        u32x4 v = pfb[K & 3][i];
        u32x2 hi, lo;
        hi.x = (v.x & 0xffffu) | (v.y << 16);
        hi.y = (v.z & 0xffffu) | (v.w << 16);
        lo.x = (v.x >> 16) | (v.y & 0xffff0000u);
        lo.y = (v.z >> 16) | (v.w & 0xffff0000u);
        *(u32x2*)(Bb + rc8[i]) = hi;
        *(u32x2*)(Bb + 17408 + rc8[i]) = lo;
      }
    };
    auto comp = [&](auto Kc) {
      constexpr int K = decltype(Kc)::v;
      const char* Bb = lds + (K & 1) * 34816;
#pragma unroll
      for (int kc = 0; kc < 4; ++kc) {
        f16x8 aH = *(const f16x8*)(Bb + rdoff + kc * 64);
        f16x8 aL = *(const f16x8*)(Bb + 17408 + rdoff + kc * 64);
        const int wo = K * 256 + kc * 64;
#pragma unroll
        for (int g = 0; g < 4; ++g) {
          f16x8 wH = *(const f16x8*)(wbH[g] + wo);
          f16x8 wL = *(const f16x8*)(wbL[g] + wo);
          accM[g] = MFMA16(aH, wH, accM[g]);
          accC[g] = MFMA16(aL, wH, accC[g]);
          accC[g] = MFMA16(aH, wL, accC[g]);
        }
        if (doy) {
          f16x8 wy = *(const f16x8*)(wbY + wo);
          accyM = MFMA16(aH, wy, accyM);
          accyC = MFMA16(aL, wy, accyC);
        }
      }
    };

    // prefetch 4 chunks deep
    issue(IC<0>{}); issue(IC<1>{}); issue(IC<2>{}); issue(IC<3>{});

    // accumulator init
#pragma unroll
    for (int r = 0; r < 4; ++r) {
#pragma unroll
      for (int g = 0; g < 4; ++g) { accM[g][r] = biasRv[r * 4 + g]; accC[g][r] = 0.f; }
      accyM[r] = bo; accyC[r] = 0.f;
    }
    if (t == 0) {
#pragma unroll
      for (int r = 0; r < 4; ++r) {
        size_t bi = (size_t)(bD0 + r) * G4 + nt * 16 + l15;
#pragma unroll
        for (int g = 0; g < 4; ++g) accM[g][r] = biasS[bi + (size_t)g * HID];
      }
    }

    waitvm<24>(); dswr(IC<0>{}); LDSBAR(); issue(IC<4>{}); comp(IC<0>{});
    waitvm<24>(); dswr(IC<1>{}); LDSBAR(); issue(IC<5>{}); comp(IC<1>{});
    waitvm<24>(); dswr(IC<2>{}); LDSBAR(); issue(IC<6>{}); comp(IC<2>{});
    waitvm<24>(); dswr(IC<3>{}); LDSBAR(); issue(IC<7>{}); comp(IC<3>{});
    waitvm<24>(); dswr(IC<4>{}); LDSBAR(); comp(IC<4>{});
    waitvm<16>(); dswr(IC<5>{}); LDSBAR(); comp(IC<5>{});
    waitvm<8>();  dswr(IC<6>{}); LDSBAR(); comp(IC<6>{});
    waitvm<0>();  dswr(IC<7>{}); LDSBAR(); comp(IC<7>{});

    // LSTM cell (fp32), packed h_{t+1} store
#pragma unroll
    for (int r = 0; r < 4; ++r) {
      float zi = accM[0][r] + accC[0][r] * LOINV;
      float zf = accM[1][r] + accC[1][r] * LOINV;
      float zg = accM[2][r] + accC[2][r] * LOINV;
      float zo = accM[3][r] + accC[3][r] * LOINV;
      float ig = fsig(zi);
      float fg = fsig(zf);
      float gg = ftanh_(zg);
      float og = fsig(zo);
      float cn = fg * c[r] + ig * gg;
      c[r] = cn;
      float hn = og * ftanh_(cn);
      _Float16 hi = (_Float16)hn;
      _Float16 lo = (_Float16)((hn - (float)hi) * LOSCALE);
      unsigned hu = (unsigned)__builtin_bit_cast(unsigned short, hi)
                  | ((unsigned)__builtin_bit_cast(unsigned short, lo) << 16);
      stg_sc_u32(hb0[r] + parout, hu);
    }
    if (doy && t > 0) {
      int tb = t - 1;
#pragma unroll
      for (int r = 0; r < 4; ++r) {
        float v = (tb < mylen[r]) ? (accyM[r] + accyC[r] * LOINV) : 0.0f;
        stg_sc_f32(out + ((size_t)(bD0 + r) * TLEN + tb) * OUTD + oy, v);
      }
    }

    // ---- per-mt barrier: 8 spread arrival lines + wave-parallel poll ----
    asm volatile("s_waitcnt vmcnt(0)" ::: "memory");
    __syncthreads();
    if (tid < 64) {
      if (tid == 0)
        __hip_atomic_fetch_add(myarr, 1u, __ATOMIC_RELAXED, __HIP_MEMORY_SCOPE_AGENT);
      if (t < TLEN - 1 || doy) {
        unsigned tgt = 8u * (unsigned)(t + 1);
        long guard = 0;
        for (;;) {
          unsigned v = tgt;
          if (tid < 8)
            v = __hip_atomic_load(bar + (size_t)(mt * 8 + tid) * 64,
                                  __ATOMIC_RELAXED, __HIP_MEMORY_SCOPE_AGENT);
          if (__ballot(v >= tgt) == ~0ull) break;
          if (++guard > 2000000L) break;   // tripwire: fail visibly, don't hang
          __builtin_amdgcn_s_sleep(2);
        }
      }
    }
    __syncthreads();
  }

  // epilogue: y_{511} = Wout*h_512 + bout   (h_512 in parity-0 buffer)
  if (doy) {
    f32x4 aM, aC;
#pragma unroll
    for (int r = 0; r < 4; ++r) { aM[r] = bo; aC[r] = 0.f; }
    const unsigned* ebase = hI + (size_t)(mt * 64 + rowA) * 1024 + lh * 8;
    for (int b = 0; b < 8; ++b) {
      u32x4 e[8];
#pragma unroll
      for (int u = 0; u < 8; ++u) {
        int kcl = u >> 1, half = u & 1;
        e[u] = ldg_sc_u4(ebase + b * 128 + kcl * 32 + half * 4);
      }
      asm volatile("s_waitcnt vmcnt(0)" ::: "memory");
      __builtin_amdgcn_sched_barrier(0);
#pragma unroll
      for (int kcl = 0; kcl < 4; ++kcl) {
        union { unsigned u[4]; f16x8 v; } H, L;
        u32x4 d0 = e[kcl * 2], d1 = e[kcl * 2 + 1];
        H.u[0] = (d0.x & 0xffffu) | (d0.y << 16);
        H.u[1] = (d0.z & 0xffffu) | (d0.w << 16);
        H.u[2] = (d1.x & 0xffffu) | (d1.y << 16);
        H.u[3] = (d1.z & 0xffffu) | (d1.w << 16);
        L.u[0] = (d0.x >> 16) | (d0.y & 0xffff0000u);
        L.u[1] = (d0.z >> 16) | (d0.w & 0xffff0000u);
        L.u[2] = (d1.x >> 16) | (d1.y & 0xffff0000u);
        L.u[3] = (d1.z >> 16) | (d1.w & 0xffff0000u);
        f16x8 wy = *(const f16x8*)(wbY + b * 256 + kcl * 64);
        aM = MFMA16(H.v, wy, aM);
        aC = MFMA16(L.v, wy, aC);
      }
    }
#pragma unroll
    for (int r = 0; r < 4; ++r) {
      float v = ((TLEN - 1) < mylen[r]) ? (aM[r] + aC[r] * LOINV) : 0.0f;
      stg_sc_f32(out + ((size_t)(bD0 + r) * TLEN + (TLEN - 1)) * OUTD + oy, v);
    }
  }
}

// ---------------- host ----------------

extern "C" void kernel_launch(void* const* d_in, const int* in_sizes, int n_in,
                              void* d_out, int out_size, void* d_ws, size_t ws_size,
                              hipStream_t stream)
{
  const float* lat  = (const float*)d_in[0];
  const float* cond = (const float*)d_in[1];
  const int*   len  = (const int*)d_in[2];
  const float* Wh   = (const float*)d_in[3];
  const float* bh   = (const float*)d_in[4];
  const float* Wc   = (const float*)d_in[5];
  const float* bc   = (const float*)d_in[6];
  const float* Ws   = (const float*)d_in[7];
  const float* bs   = (const float*)d_in[8];
  const float* Wih  = (const float*)d_in[9];
  const float* Whh  = (const float*)d_in[10];
  const float* bih  = (const float*)d_in[11];
  const float* bhh  = (const float*)d_in[12];
  const float* Wout = (const float*)d_in[13];
  const float* bout = (const float*)d_in[14];
  float* out = (float*)d_out;

  char* ws = (char*)d_ws;
  size_t off = 0;
  auto alloc = [&](size_t bytes) -> void* {
    void* p = ws + off;
    off += (bytes + 255) & ~(size_t)255;
    return p;
  };
  unsigned* hI    = (unsigned*)alloc((size_t)2 * BB * HID * 4);   // packed {hi,lo} f16
  float*    c0    = (float*)alloc((size_t)BB * HID * 4);
  float*    h0    = (float*)alloc((size_t)BB * HID * 4);
  float*    x0    = (float*)alloc((size_t)BB * OUTD * 4);
  float*    dxy   = (float*)alloc((size_t)BB * OUTD * 4);
  _Float16* Wob   = (_Float16*)alloc((size_t)OUTD * HID * 2);
  _Float16* WeffH = (_Float16*)alloc((size_t)G4 * HID * 2);
  _Float16* WeffL = (_Float16*)alloc((size_t)G4 * HID * 2);
  float*    biasR = (float*)alloc((size_t)BB * G4 * 4);
  float*    biasS = (float*)alloc((size_t)BB * G4 * 4);
  unsigned* bar   = (unsigned*)alloc(4 * 8 * 64 * 4);             // 32 lines, 256B apart
  if (off > ws_size) return;

  hipMemsetAsync(bar, 0, 4 * 8 * 64 * 4, stream);

  prep_init<<<dim3(9, 32),   256, 0, stream>>>(lat, Wh, bh, Wc, bc, Ws, bs, h0, hI, c0, x0);
  prep_weff<<<dim3(4, 256),  256, 0, stream>>>(Whh, Wih, Wout, WeffH, WeffL);
  prep_wob <<<dim3(512),     256, 0, stream>>>(Wout, Wob);
  prep_d   <<<dim3(128),     256, 0, stream>>>(h0, Wout, bout, x0, dxy);
  prep_bias<<<dim3(16, 32),  256, 0, stream>>>(cond, Wih, bih, bhh, bout, dxy, biasR, biasS);
  lstm_main<<<dim3(256),     256, 0, stream>>>(hI, c0, biasR, biasS, WeffH, WeffL, Wob, bout, len, out, bar);
}